// Round 12
// baseline (32414.597 us; speedup 1.0000x reference)
//
#include <hip/hip_runtime.h>
#include <cstddef>

#define HID   256
#define CTXD  128
#define QDIM  128
#define VDNUM 33

typedef float  float4e __attribute__((ext_vector_type(4)));
typedef unsigned int uint4e __attribute__((ext_vector_type(4)));
typedef unsigned int uint2e __attribute__((ext_vector_type(2)));
typedef _Float16 half2e __attribute__((ext_vector_type(2)));

__device__ __forceinline__ float sigf(float x) { return 1.f / (1.f + expf(-x)); }

union H8 { uint4e u; half2e d[4]; _Float16 h[8]; };
union H4 { uint2e u; _Float16 h[4]; };

struct P {
    const int*   seqs;
    const float* key; const float* val; const float* embed;
    const float* Wih0; const float* Whh0; const float* bih0; const float* bhh0;
    const float* Wih1; const float* Whh1; const float* bih1; const float* bhh1;
    const float* Wih2; const float* Whh2; const float* bih2; const float* bhh2;
    const float* Wq;  const float* bq;
    const float* Ws1; const float* bs1;
    const float* Ws2; const float* bs2;
    const float* h0; const float* c0; const float* con;
    unsigned short* WH0; unsigned short* WH1; unsigned short* WH2;  // fp16 LSTM weights
    unsigned short* Ws1h;                                           // fp16 MLP1 weights
    float* bsum; float* WqT4; float* Ws2T; float* Ep;
    unsigned short* keyh; unsigned short* valh;                     // fp16 key/val copies
    int dokv;
    float* outS; float* outP;
    int S, T;
};

// ---------------------------------------------------------------------------
// One-time repack (every call, deterministic). Layouts identical to round 10.
// ---------------------------------------------------------------------------
__global__ void prep(P p)
{
    const int stride = gridDim.x * blockDim.x;
    const int i0 = blockIdx.x * blockDim.x + threadIdx.x;
    const int T = p.T;

    // Ep[c][r] = sum_k embed[c][k] * Wih0[r][k], k<256 (exact fp32)
    for (int z = i0; z < VDNUM * 1024; z += stride) {
        int c = z >> 10, r = z & 1023;
        const float* w = p.Wih0 + (size_t)r * 384;
        const float* e = p.embed + c * HID;
        float a = 0.f;
        #pragma unroll 8
        for (int k = 0; k < HID; ++k) a += e[k] * w[k];
        p.Ep[z] = a;
    }

    _Float16* w0 = (_Float16*)p.WH0;
    for (int z = i0; z < 48 * 8192; z += stride) {           // L0: K=384 = [ctx|h]
        int c = z >> 13, rem = z & 8191, r = rem >> 3, j = rem & 7;
        int k = c * 8 + j;
        float v = (k < 128) ? p.Wih0[(size_t)r * 384 + 256 + k]
                            : p.Whh0[(size_t)r * 256 + (k - 128)];
        w0[z] = (_Float16)v;
    }
    _Float16* w1 = (_Float16*)p.WH1;
    _Float16* w2 = (_Float16*)p.WH2;
    for (int z = i0; z < 64 * 8192; z += stride) {           // L1,L2: K=512
        int c = z >> 13, rem = z & 8191, r = rem >> 3, j = rem & 7;
        int k = c * 8 + j;
        w1[z] = (_Float16)((k < 256) ? p.Wih1[(size_t)r * 256 + k]
                                     : p.Whh1[(size_t)r * 256 + (k - 256)]);
        w2[z] = (_Float16)((k < 256) ? p.Wih2[(size_t)r * 256 + k]
                                     : p.Whh2[(size_t)r * 256 + (k - 256)]);
    }
    _Float16* ws1 = (_Float16*)p.Ws1h;
    for (int z = i0; z < 48 * 2048; z += stride) {           // Ws1: [256 j][384 k]
        int c = z >> 11, rem = z & 2047, j = rem >> 3, lane = rem & 7;
        int k = c * 8 + lane;
        ws1[z] = (_Float16)p.Ws1[(size_t)j * 384 + k];
    }
    for (int z = i0; z < 3072; z += stride) {                // bih+bhh fused
        int l = z >> 10, r = z & 1023;
        const float* bi = l == 0 ? p.bih0 : l == 1 ? p.bih1 : p.bih2;
        const float* bh = l == 0 ? p.bhh0 : l == 1 ? p.bhh1 : p.bhh2;
        p.bsum[z] = bi[r] + bh[r];
    }
    for (int z = i0; z < 256 * 128; z += stride) {           // WqT4 [k4][128][4] fp32
        int k = z >> 7, q = z & 127;
        p.WqT4[((size_t)(k >> 2) * 128 + q) * 4 + (k & 3)] = p.Wq[(size_t)q * HID + k];
    }
    for (int z = i0; z < 256 * VDNUM; z += stride) {         // Ws2T [k][33] fp32
        int k = z / VDNUM, v = z - k * VDNUM;
        p.Ws2T[(size_t)k * VDNUM + v] = p.Ws2[(size_t)v * HID + k];
    }
    if (p.dokv) {
        _Float16* kh = (_Float16*)p.keyh;
        _Float16* vh = (_Float16*)p.valh;
        const int NKV = 64 * QDIM * T;
        for (int z = i0; z < NKV; z += stride) kh[z] = (_Float16)p.key[z];
        for (int z = i0; z < NKV; z += stride) vh[z] = (_Float16)p.val[z];
    }
}

#define FD(acc, wd, xv) acc = __builtin_amdgcn_fdot2(wd, xv, acc, false);

// Consume one 4-chunk register set (32 halves of x) then reload it 16 chunks
// ahead (pad chunks absorb the final overrun). Zero rotation movs.
#define SET4(S0, S1, S2, S3, XB) \
    FD(a0, S0.d[0], xx[XB+0])  FD(a1, S0.d[1], xx[XB+1]) \
    FD(a0, S0.d[2], xx[XB+2])  FD(a1, S0.d[3], xx[XB+3]) \
    S0.u = w[nb];              nb += 1024; \
    FD(a0, S1.d[0], xx[XB+4])  FD(a1, S1.d[1], xx[XB+5]) \
    FD(a0, S1.d[2], xx[XB+6])  FD(a1, S1.d[3], xx[XB+7]) \
    S1.u = w[nb];              nb += 1024; \
    FD(a0, S2.d[0], xx[XB+8])  FD(a1, S2.d[1], xx[XB+9]) \
    FD(a0, S2.d[2], xx[XB+10]) FD(a1, S2.d[3], xx[XB+11]) \
    S2.u = w[nb];              nb += 1024; \
    FD(a0, S3.d[0], xx[XB+12]) FD(a1, S3.d[1], xx[XB+13]) \
    FD(a0, S3.d[2], xx[XB+14]) FD(a1, S3.d[3], xx[XB+15]) \
    S3.u = w[nb];              nb += 1024;

// ---------------------------------------------------------------------------
// LSTM matvec via v_dot2_f32_f16: thread owns gate-row `tid`; 4 register sets
// x 4 chunks, unrolled by 16 chunks, in-place reload (no rotation movs),
// ~256 B/thread in flight. x is fp16 in LDS (broadcast reads).
// ---------------------------------------------------------------------------
template<int NCH>   // multiple of 16: 48 (L0) or 64 (L1/L2)
__device__ __forceinline__ float matvec_dot2(const unsigned short* W, int tid, const _Float16* x)
{
    const uint4e* w = (const uint4e*)W + tid;     // chunk stride = 1024 uint4e
    H8 A0, A1, A2, A3, B0, B1, B2, B3, C0, C1, C2, C3, D0, D1, D2, D3;
    A0.u = w[0];     A1.u = w[1024];  A2.u = w[2048];  A3.u = w[3072];
    B0.u = w[4096];  B1.u = w[5120];  B2.u = w[6144];  B3.u = w[7168];
    C0.u = w[8192];  C1.u = w[9216];  C2.u = w[10240]; C3.u = w[11264];
    D0.u = w[12288]; D1.u = w[13312]; D2.u = w[14336]; D3.u = w[15360];
    float a0 = 0.f, a1 = 0.f;
    for (int c = 0; c < NCH; c += 16) {
        const half2e* xx = (const half2e*)(x + c * 8);
        size_t nb = (size_t)(c + 16) * 1024;      // pad chunks absorb overrun
        SET4(A0, A1, A2, A3, 0)
        SET4(B0, B1, B2, B3, 16)
        SET4(C0, C1, C2, C3, 32)
        SET4(D0, D1, D2, D3, 48)
    }
    return a0 + a1;
}

// ---------------------------------------------------------------------------
// Persistent per-batch-element kernel: 64 blocks x 1024 threads, zero
// device-scope sync. fp16 weights AND fp16 activations (dot2 operands);
// cell state c and all softmax/score math stay fp32.
// ---------------------------------------------------------------------------
template<bool KV16>
__global__ __launch_bounds__(1024, 4) void speller(P p)
{
    __shared__ float h[3][HID], c[3][HID], ctx[CTXD];
    __shared__ __align__(16) _Float16 xh0h[384];   // L0 input [ctx|h0] fp16
    __shared__ __align__(16) _Float16 xh12h[512];  // L1/L2 input fp16
    __shared__ __align__(16) _Float16 feath[384];  // MLP1 feat [h2|ctx] fp16
    __shared__ float gacc[1024];
    __shared__ float qry[QDIM];
    __shared__ float s_sc[2048];
    __shared__ float4e ep[4][256];
    __shared__ float red[16][CTXD];
    __shared__ float hid[HID];
    __shared__ float predp[VDNUM * 8];
    __shared__ float predv[VDNUM];
    __shared__ float wred[16];
    __shared__ float bcast;
    __shared__ int   chr;

    const int b   = blockIdx.x;
    const int tid = threadIdx.x;
    const int T   = p.T;
    const int T4  = T >> 2;
    const int n   = p.seqs[b];

    if (tid < HID) {
        #pragma unroll
        for (int l = 0; l < 3; ++l) { h[l][tid] = p.h0[l * HID + tid]; c[l][tid] = p.c0[l * HID + tid]; }
    }
    if (tid < CTXD) ctx[tid] = p.con[tid];
    if (tid == 0)   chr = 0;
    __syncthreads();

    for (int s = 0; s < p.S; ++s) {
        // ---- build L0 input (fp16): [ctx | h0_old]; embed part from Ep ----
        if (tid < 128)      xh0h[tid] = (_Float16)ctx[tid];
        else if (tid < 384) xh0h[tid] = (_Float16)h[0][tid - 128];
        __syncthreads();

        // ---- L0 (K=384, 48 chunks) + Ep lookup ----
        gacc[tid] = p.bsum[tid] + p.Ep[(size_t)chr * 1024 + tid]
                  + matvec_dot2<48>(p.WH0, tid, xh0h);
        __syncthreads();
        if (tid < HID) {   // gate order i,f,g,o
            float gi = gacc[tid], gf = gacc[256 + tid], gg = gacc[512 + tid], go = gacc[768 + tid];
            float cn = sigf(gf) * c[0][tid] + sigf(gi) * tanhf(gg);
            c[0][tid] = cn;
            float hn = sigf(go) * tanhf(cn);
            h[0][tid] = hn;
            xh12h[tid] = (_Float16)hn; xh12h[256 + tid] = (_Float16)h[1][tid];
        }
        __syncthreads();

        // ---- L1 (K=512, 64 chunks) ----
        gacc[tid] = p.bsum[1024 + tid] + matvec_dot2<64>(p.WH1, tid, xh12h);
        __syncthreads();
        if (tid < HID) {
            float gi = gacc[tid], gf = gacc[256 + tid], gg = gacc[512 + tid], go = gacc[768 + tid];
            float cn = sigf(gf) * c[1][tid] + sigf(gi) * tanhf(gg);
            c[1][tid] = cn;
            float hn = sigf(go) * tanhf(cn);
            h[1][tid] = hn;
            xh12h[tid] = (_Float16)hn; xh12h[256 + tid] = (_Float16)h[2][tid];
        }
        __syncthreads();

        // ---- L2 (K=512, 64 chunks) ----
        gacc[tid] = p.bsum[2048 + tid] + matvec_dot2<64>(p.WH2, tid, xh12h);
        __syncthreads();
        if (tid < HID) {
            float gi = gacc[tid], gf = gacc[256 + tid], gg = gacc[512 + tid], go = gacc[768 + tid];
            float cn = sigf(gf) * c[2][tid] + sigf(gi) * tanhf(gg);
            c[2][tid] = cn;
            h[2][tid] = sigf(go) * tanhf(cn);
        }
        __syncthreads();

        // ---- query = h2 @ Wq^T + bq (fp32 — kept full precision) ----
        {
            const int q = tid & 127, ch = tid >> 7;
            const float4e* w = (const float4e*)p.WqT4 + q;
            float a = 0;
            #pragma unroll
            for (int i = 0; i < 8; ++i) {
                int k4 = ch * 8 + i;
                float4e wv = w[(size_t)k4 * 128];
                const float* x = &h[2][k4 * 4];
                a += x[0] * wv.x + x[1] * wv.y + x[2] * wv.z + x[3] * wv.w;
            }
            gacc[ch * 128 + q] = a;
        }
        __syncthreads();
        if (tid < QDIM) {
            float a = p.bq[tid];
            #pragma unroll
            for (int i = 0; i < 8; ++i) a += gacc[i * 128 + tid];
            qry[tid] = a;
        }
        __syncthreads();

        // ---- energy: 2 passes over t-halves; thread = (t4 slot, q-group) ----
        {
            const int tl = tid & 255, qg = tid >> 8;
            #pragma unroll
            for (int half = 0; half < 2; ++half) {
                const int t0 = half << 10;
                float4e e = {0.f, 0.f, 0.f, 0.f};
                if (t0 < n) {
                    const int q0 = qg * 32;
                    if (KV16) {
                        const uint2e* k2 = (const uint2e*)p.keyh
                            + (((size_t)b * QDIM * T + t0) >> 2) + tl;
                        #pragma unroll 8
                        for (int qq = 0; qq < 32; ++qq) {
                            H4 kv; kv.u = k2[(size_t)(q0 + qq) * (T >> 2)];
                            float qv = qry[q0 + qq];
                            e.x += qv * (float)kv.h[0];
                            e.y += qv * (float)kv.h[1];
                            e.z += qv * (float)kv.h[2];
                            e.w += qv * (float)kv.h[3];
                        }
                    } else {
                        const float4e* k4 = (const float4e*)p.key + (size_t)b * QDIM * T4
                                          + (t0 >> 2) + tl;
                        #pragma unroll 8
                        for (int qq = 0; qq < 32; ++qq) {
                            float4e kv = k4[(size_t)(q0 + qq) * T4];
                            e += qry[q0 + qq] * kv;
                        }
                    }
                }
                ep[qg][tl] = e;
                __syncthreads();
                if (tid < 256 && t0 < n) {
                    float4e r = (ep[0][tid] + ep[1][tid]) + (ep[2][tid] + ep[3][tid]);
                    ((float4e*)s_sc)[(t0 >> 2) + tid] = r;
                }
                __syncthreads();
            }
        }

        // ---- max over t<n ----
        float m = -INFINITY;
        for (int t = tid; t < n; t += 1024) m = fmaxf(m, s_sc[t]);
        #pragma unroll
        for (int off = 32; off; off >>= 1) m = fmaxf(m, __shfl_xor(m, off));
        if ((tid & 63) == 0) wred[tid >> 6] = m;
        __syncthreads();
        if (tid == 0) {
            float r = wred[0];
            #pragma unroll
            for (int i = 1; i < 16; ++i) r = fmaxf(r, wred[i]);
            bcast = r;
        }
        __syncthreads();
        m = bcast;

        // ---- exp + sum ----
        float z = 0.f;
        for (int t = tid; t < T; t += 1024) {
            float pv = 0.f;
            if (t < n) { pv = expf(s_sc[t] - m); z += pv; }
            s_sc[t] = pv;
        }
        #pragma unroll
        for (int off = 32; off; off >>= 1) z += __shfl_xor(z, off);
        if ((tid & 63) == 0) wred[tid >> 6] = z;
        __syncthreads();
        if (tid == 0) {
            float r = 0.f;
            #pragma unroll
            for (int i = 0; i < 16; ++i) r += wred[i];
            bcast = r;
        }
        __syncthreads();
        const float Z = bcast;

        // ---- scores out ----
        float* so = p.outS + ((size_t)b * p.S + s) * T;
        for (int t = tid; t < T; t += 1024) {
            float sc = s_sc[t] / Z;
            s_sc[t] = sc;
            __builtin_nontemporal_store(sc, so + t);
        }
        __syncthreads();

        // ---- ctx = sum_{t<n} score[t] * val[b][t][:] ----
        {
            const int tg = tid >> 5, cq = tid & 31;
            float ax = 0, ay = 0, az = 0, aw = 0;
            if (KV16) {
                const uint2e* v2 = (const uint2e*)p.valh + (size_t)b * T * 32 + cq;
                #pragma unroll 4
                for (int t = tg; t < n; t += 32) {
                    float sv = s_sc[t];
                    H4 vv; vv.u = v2[(size_t)t * 32];
                    ax += sv * (float)vv.h[0]; ay += sv * (float)vv.h[1];
                    az += sv * (float)vv.h[2]; aw += sv * (float)vv.h[3];
                }
            } else {
                const float4e* v4 = (const float4e*)p.val + (size_t)b * T * 32 + cq;
                #pragma unroll 4
                for (int t = tg; t < n; t += 32) {
                    float   sv = s_sc[t];
                    float4e vv = v4[(size_t)t * 32];
                    ax += sv * vv.x; ay += sv * vv.y; az += sv * vv.z; aw += sv * vv.w;
                }
            }
            ax += __shfl_xor(ax, 32); ay += __shfl_xor(ay, 32);
            az += __shfl_xor(az, 32); aw += __shfl_xor(aw, 32);
            if ((tid & 63) < 32) {
                const int w = tid >> 6;
                red[w][cq * 4 + 0] = ax; red[w][cq * 4 + 1] = ay;
                red[w][cq * 4 + 2] = az; red[w][cq * 4 + 3] = aw;
            }
        }
        __syncthreads();
        if (tid < CTXD) {
            float a = 0.f;
            #pragma unroll
            for (int w = 0; w < 16; ++w) a += red[w][tid];
            ctx[tid] = a;
            feath[256 + tid] = (_Float16)a;        // feat = [h2 | ctx_new]
        }
        if (tid < HID) feath[tid] = (_Float16)h[2][tid];
        __syncthreads();

        // ---- MLP1: hid = relu(feat @ Ws1^T + bs1), dot2 ----
        {
            const int j = tid & 255, ch = tid >> 8;
            const uint4e* w = (const uint4e*)p.Ws1h + (size_t)(ch * 12) * 256 + j;
            H8 cc; cc.u = w[0];
            float a0 = 0.f, a1 = 0.f;
            #pragma unroll 2
            for (int u = 0; u < 12; ++u) {
                H8 nx; nx.u = w[(size_t)(u + 1) * 256];   // pad chunk absorbs overrun
                const half2e* xx = (const half2e*)(feath + (ch * 12 + u) * 8);
                FD(a0, cc.d[0], xx[0]) FD(a1, cc.d[1], xx[1])
                FD(a0, cc.d[2], xx[2]) FD(a1, cc.d[3], xx[3])
                cc = nx;
            }
            gacc[ch * 256 + j] = a0 + a1;
        }
        __syncthreads();
        if (tid < HID)
            hid[tid] = fmaxf(p.bs1[tid] + ((gacc[tid] + gacc[256 + tid]) + (gacc[512 + tid] + gacc[768 + tid])), 0.f);
        __syncthreads();

        // ---- predict = hid @ Ws2^T + bs2 (fp32); argmax feedback ----
        if (tid < VDNUM * 8) {
            const int v = tid >> 3, oct = tid & 7;
            const float* w2 = p.Ws2T + (size_t)oct * 32 * VDNUM + v;
            float a = 0.f;
            #pragma unroll 8
            for (int k = 0; k < 32; ++k) a += hid[oct * 32 + k] * w2[(size_t)k * VDNUM];
            predp[v * 8 + oct] = a;
        }
        __syncthreads();
        if (tid < VDNUM) {
            float a = p.bs2[tid];
            #pragma unroll
            for (int o = 0; o < 8; ++o) a += predp[tid * 8 + o];
            __builtin_nontemporal_store(a, p.outP + ((size_t)b * p.S + s) * VDNUM + tid);
            predv[tid] = a;
        }
        __syncthreads();
        if (tid == 0) {   // first-occurrence argmax (strict >)
            int best = 0; float bv = predv[0];
            for (int v = 1; v < VDNUM; ++v) if (predv[v] > bv) { bv = predv[v]; best = v; }
            chr = best;
        }
        __syncthreads();
    }
}

extern "C" void kernel_launch(void* const* d_in, const int* in_sizes, int n_in,
                              void* d_out, int out_size, void* d_ws, size_t ws_size,
                              hipStream_t stream)
{
    P p;
    p.seqs  = (const int*)  d_in[0];
    p.key   = (const float*)d_in[1];
    p.val   = (const float*)d_in[2];
    p.embed = (const float*)d_in[4];
    p.Wih0  = (const float*)d_in[5];  p.Whh0 = (const float*)d_in[6];
    p.bih0  = (const float*)d_in[7];  p.bhh0 = (const float*)d_in[8];
    p.Wih1  = (const float*)d_in[9];  p.Whh1 = (const float*)d_in[10];
    p.bih1  = (const float*)d_in[11]; p.bhh1 = (const float*)d_in[12];
    p.Wih2  = (const float*)d_in[13]; p.Whh2 = (const float*)d_in[14];
    p.bih2  = (const float*)d_in[15]; p.bhh2 = (const float*)d_in[16];
    p.Wq    = (const float*)d_in[17]; p.bq   = (const float*)d_in[18];
    p.Ws1   = (const float*)d_in[19]; p.bs1  = (const float*)d_in[20];
    p.Ws2   = (const float*)d_in[21]; p.bs2  = (const float*)d_in[22];
    p.h0    = (const float*)d_in[23];
    p.c0    = (const float*)d_in[24];
    p.con   = (const float*)d_in[25];

    const int B = in_sizes[0];                  // 64
    p.T = in_sizes[1] / (B * QDIM);             // 2048
    p.S = in_sizes[3] / B;                      // 220

    // workspace layout (bytes; 16B-aligned) — identical to round 10
    char* ws = (char*)d_ws;
    p.WH0  = (unsigned short*)(ws + 0);          // 64 chunks  = 1,048,576 B
    p.WH1  = (unsigned short*)(ws + 1048576);    // 80 chunks  = 1,310,720 B
    p.WH2  = (unsigned short*)(ws + 2359296);    // 1,310,720 B
    p.Ws1h = (unsigned short*)(ws + 3670016);    //   200,704 B
    p.bsum = (float*)(ws + 3870720);             //    12,288 B
    p.WqT4 = (float*)(ws + 3883008);             //   131,072 B
    p.Ws2T = (float*)(ws + 4014080);             //    33,792 B
    p.Ep   = (float*)(ws + 4047872);             //   135,168 B  -> end 4,183,040

    const size_t kvBytes = (size_t)B * QDIM * p.T * 2;
    p.keyh = (unsigned short*)(ws + 4183040);
    p.valh = (unsigned short*)(ws + 4183040 + kvBytes);
    p.dokv = (ws_size >= 4183040 + 2 * kvBytes) ? 1 : 0;

    p.outS = (float*)d_out;
    p.outP = p.outS + (size_t)B * p.S * p.T;

    prep<<<1024, 256, 0, stream>>>(p);
    if (p.dokv) speller<true ><<<B, 1024, 0, stream>>>(p);
    else        speller<false><<<B, 1024, 0, stream>>>(p);
}